// Round 6
// baseline (303.240 us; speedup 1.0000x reference)
//
#include <hip/hip_runtime.h>
#include <hip/hip_bf16.h>
#include <stdint.h>
#include <stddef.h>

#define D_MODEL 2048
#define NOUT    2048      // SLOTS * D_FIELD
#define BATCH   2
#define SEQ     4096
#define M_TOTAL (BATCH*SEQ)   // 8192
#define SLOTS   8
#define D_FIELD 256
#define CHUNK   32            // carry granularity (2 fragment rows)
#define NCHUNK  (SEQ/CHUNK)   // 128
#define NWAVEC  64            // per-batch wave-carry slots (128 rows each)

typedef __attribute__((ext_vector_type(4))) float  floatx4;
typedef __attribute__((ext_vector_type(8))) __bf16 bf16x8;
typedef __attribute__((ext_vector_type(4))) __bf16 bf16x4;

// ---------------------------------------------------------------------------
__device__ __forceinline__ void async_copy16(const void* gsrc, void* ldst) {
  __builtin_amdgcn_global_load_lds(
      (__attribute__((address_space(1))) const void*)(uintptr_t)gsrc,
      (__attribute__((address_space(3))) void*)(uintptr_t)ldst,
      16, 0, 0);
}

// ---------------------------------------------------------------------------
// Kernel 1: cast x and W fp32 -> bf16 into workspace; also zero barrier ctrs.
__global__ void cast_kernel(const float* __restrict__ x,
                            const float* __restrict__ W,
                            __bf16* __restrict__ xb,
                            __bf16* __restrict__ wb,
                            int* __restrict__ ctr) {
  if (blockIdx.x == 0 && threadIdx.x < 8)
    __hip_atomic_store(&ctr[threadIdx.x], 0, __ATOMIC_RELAXED, __HIP_MEMORY_SCOPE_AGENT);
  const long long nx = (long long)M_TOTAL * D_MODEL;  // 16777216
  const long long nw = (long long)NOUT * D_MODEL;     // 4194304
  long long base = ((long long)blockIdx.x * blockDim.x + threadIdx.x) * 4;
  if (base < nx) {
    float4 v = *(const float4*)(x + base);
    bf16x4 o;
    o[0] = (__bf16)v.x; o[1] = (__bf16)v.y; o[2] = (__bf16)v.z; o[3] = (__bf16)v.w;
    *(bf16x4*)(xb + base) = o;
  } else {
    long long j = base - nx;
    if (j < nw) {
      float4 v = *(const float4*)(W + j);
      bf16x4 o;
      o[0] = (__bf16)v.x; o[1] = (__bf16)v.y; o[2] = (__bf16)v.z; o[3] = (__bf16)v.w;
      *(bf16x4*)(wb + j) = o;
    }
  }
}

// ---------------------------------------------------------------------------
// Kernel 2: 256x256 GEMM + fused full scan.
// R6 (single axis): ds_read ONE PHASE AHEAD -> DS pipe overlaps MFMA pipe.
// R4/R5 phases were {reads for THIS MFMA; BAR; drain; MFMA} -> per-CU strict
// alternation DS-burst / MFMA-burst (sum ~4000+ cyc/tile vs max ~2500) = the
// measured 2x gap over the 33us MFMA floor (R5 falsified the vmcnt theory).
// New phase: {reads for NEXT phase's MFMA; stage; [vmcnt]; BAR; MFMA(regs
// loaded LAST phase)}. Compiler inserts counted lgkm waits (leaves this
// phase's 4-8 reads in flight); sched_barrier(0) at BAR pins motion.
// Per tile T (buf = T&1; quadrants Q0..Q3 as before):
//   tp0: RD bfr1(T)[buf];     STG Bu1(T+1)->buf^1; VMW6; BAR; Q0(aflo,bfr0c)
//   tp1: RD afhi(T)[buf];     STG Au1(T+1)->buf^1; VMW4; BAR; Q1(aflo,bfr1)
//   tp2: RD bfr0n(T+1)[buf^1];STG Au0(T+2)->buf;         BAR; Q2(afhi,bfr1)
//   tp3: RD aflo(T+1)[buf^1]; STG Bu0(T+2)->buf;   VMW6; BAR; Q3(afhi,bfr0c)
// Read certification (unit drained by VMW at phase p-1, read at p after BAR):
//   bfr1(T)@tp0 <- Bu1(T)@T-1.tp0, drained T-1.tp3 VMW6 (leave Au1,Au0',Bu0'=6)
//   afhi(T)@tp1 <- Au1(T)@T-1.tp1, drained T.tp0 VMW6 (leave Au0',Bu0',Bu1'=6)
//   bfr0(T+1)@tp2 <- Bu0(T+1)@T-1.tp3, drained T.tp1 VMW4 (leave Bu1',Au1'=4;
//                    also drains the older Au0(T+1))
//   aflo(T+1)@tp3 <- Au0(T+1)@T-1.tp2, drained T.tp1 VMW4 (in-order, older)
// LDS overwrite safety (reader lgkm-drain + >=1 BAR before stage issue):
//   Au0(T+2)->buf@tp2: aflo(T) last read T-1.tp3, drained by Q0's lgkm@tp0,
//     BAR tp1 < issue ✓.  Bu0(T+2)->buf@tp3: bfr0(T) read T-1.tp2, drained
//     T-1.tp3, BARs tp0..tp2 ✓.  B/A-hi units ->buf^1: read in T-1, 3+ BARs ✓.
// Regs: aflo/afhi split (lifetimes overlap), bfr0 double-buffered (e/o).
// Epilogue: UNCHANGED (R4-verified).
// ---------------------------------------------------------------------------
#define VMW6 asm volatile("s_waitcnt vmcnt(6)" ::: "memory")
#define VMW4 asm volatile("s_waitcnt vmcnt(4)" ::: "memory")
#define VMW2 asm volatile("s_waitcnt vmcnt(2)" ::: "memory")
#define VMW0 asm volatile("s_waitcnt vmcnt(0)" ::: "memory")
#define BAR do{ __builtin_amdgcn_s_barrier(); __builtin_amdgcn_sched_barrier(0); }while(0)

#define DSRD(off) (*(const bf16x8*)(smem + (off)))

#define STG(GP, ROFF, DSTOFF, KTN) do{ \
  async_copy16((GP) + (ROFF) + (KTN)*64,      smem + (DSTOFF)); \
  async_copy16((GP) + (ROFF) + (KTN)*64 + 32, smem + (DSTOFF) + 1024); }while(0)

#define RD_A(BUF, MOFF, DST) do{ \
  _Pragma("unroll") for (int i_ = 0; i_ < 4; ++i_){ \
  _Pragma("unroll") for (int k_ = 0; k_ < 2; ++k_){ \
    DST[i_][k_] = DSRD((BUF)*32768 + ((wM8+(MOFF)+i_)*2+k_)*1024 + fragOff); }} }while(0)

#define RD_B(BUF, NOFF, DST) do{ \
  _Pragma("unroll") for (int j_ = 0; j_ < 2; ++j_){ \
  _Pragma("unroll") for (int k_ = 0; k_ < 2; ++k_){ \
    DST[j_][k_] = DSRD(65536 + (BUF)*32768 + ((wN4+(NOFF)+j_)*2+k_)*1024 + fragOff); }} }while(0)

#define MFMA_Q(AM, AN, AF, BF) do{ \
  __builtin_amdgcn_s_setprio(1); \
  _Pragma("unroll") for (int i_ = 0; i_ < 4; ++i_){ \
  _Pragma("unroll") for (int j_ = 0; j_ < 2; ++j_){ \
  _Pragma("unroll") for (int k_ = 0; k_ < 2; ++k_){ \
    acc[(AM)+i_][(AN)+j_] = __builtin_amdgcn_mfma_f32_16x16x32_bf16( \
        AF[i_][k_], BF[j_][k_], acc[(AM)+i_][(AN)+j_], 0, 0, 0); }}} \
  __builtin_amdgcn_s_setprio(0); }while(0)

// Full steady-state tile: stages T+1 (tp0/tp1) and T+2 (tp2/tp3).
#define KTILE_F(BUF, T1, T2, BC, BN) do{ \
  /* tp0 */ \
  RD_B(BUF, 2, bfr1); \
  STG(gB, rB1, ((BUF)^1)*32768 + dB1, T1); \
  VMW6; BAR; \
  MFMA_Q(0, 0, aflo, BC); \
  /* tp1 */ \
  RD_A(BUF, 4, afhi); \
  STG(gA, rA1, ((BUF)^1)*32768 + dA1, T1); \
  VMW4; BAR; \
  MFMA_Q(0, 2, aflo, bfr1); \
  /* tp2 */ \
  RD_B((BUF)^1, 0, BN); \
  STG(gA, rA0, (BUF)*32768 + dA0, T2); \
  BAR; \
  MFMA_Q(4, 2, afhi, bfr1); \
  /* tp3 */ \
  RD_A((BUF)^1, 0, aflo); \
  STG(gB, rB0, (BUF)*32768 + dB0, T2); \
  VMW6; BAR; \
  MFMA_Q(4, 0, afhi, BC); \
}while(0)

// Tile 30: stage only T+1 (=31); waits re-derived for the shrinking queue.
#define KTILE_T30(BUF, T1, BC, BN) do{ \
  RD_B(BUF, 2, bfr1); \
  STG(gB, rB1, ((BUF)^1)*32768 + dB1, T1); \
  VMW6; BAR; \
  MFMA_Q(0, 0, aflo, BC); \
  RD_A(BUF, 4, afhi); \
  STG(gA, rA1, ((BUF)^1)*32768 + dA1, T1); \
  VMW4; BAR; \
  MFMA_Q(0, 2, aflo, bfr1); \
  RD_B((BUF)^1, 0, BN); \
  BAR; \
  MFMA_Q(4, 2, afhi, bfr1); \
  RD_A((BUF)^1, 0, aflo); \
  VMW2; BAR; \
  MFMA_Q(4, 0, afhi, BC); \
}while(0)

// Tile 31: no stages, no next-tile reads, drain to 0.
#define KTILE_T31(BUF, BC) do{ \
  RD_B(BUF, 2, bfr1); \
  VMW0; BAR; \
  MFMA_Q(0, 0, aflo, BC); \
  RD_A(BUF, 4, afhi); \
  BAR; \
  MFMA_Q(0, 2, aflo, bfr1); \
  MFMA_Q(4, 2, afhi, bfr1); \
  MFMA_Q(4, 0, afhi, BC); \
}while(0)

#define CARRY_LD(P) __hip_atomic_load((P), __ATOMIC_RELAXED, __HIP_MEMORY_SCOPE_AGENT)

__global__ __launch_bounds__(512, 2) void gemm_scan_kernel(
    const __bf16* __restrict__ A,    // [M_TOTAL, D_MODEL] bf16
    const __bf16* __restrict__ Bw,   // [NOUT, D_MODEL] bf16
    const float*  __restrict__ bias,
    const float*  __restrict__ alphas,
    float* __restrict__ C,           // [M_TOTAL, NOUT]  -> FINAL state
    float* __restrict__ wc,          // [BATCH, NWAVEC, NOUT] per-128-row carries
    int*   __restrict__ ctr) {       // [8] per-by barrier counters
  extern __shared__ __align__(16) char smem[];
  const int t    = threadIdx.x;
  const int lane = t & 63;
  const int w    = t >> 6;        // wave 0..7
  const int wM   = w >> 2;        // 0..1
  const int wN   = w & 3;         // 0..3
  const int m0   = blockIdx.x * 256;   // m fast -> A-panel's 8 n-blocks on one XCD
  const int n0   = blockIdx.y * 256;

  const int lq = lane >> 4, lr = lane & 15;
  const int fragOff = (lr*64 + lq*16) ^ (((lr >> 3) & 1) << 5);
  const int wM8 = wM*8, wN4 = wN*4;

  // staging: lane -> (row l>>2, pre-swizzled colOff) inside a 16x32 subtile
  const int lrow = lane >> 2;
  const int lcol = ((lane & 3) * 8) ^ ((lane >> 5) * 16);
  const int srA0 = (w & 3) + ((w >> 2) << 3), srA1 = srA0 + 4;
  const int srB0 = (w & 1) + ((w >> 1) << 2), srB1 = srB0 + 2;
  const __bf16* gA = A  + (size_t)m0 * D_MODEL + lcol;
  const __bf16* gB = Bw + (size_t)n0 * D_MODEL + lcol;
  const int rA0 = (srA0*16 + lrow) * D_MODEL;
  const int rA1 = (srA1*16 + lrow) * D_MODEL;
  const int rB0 = (srB0*16 + lrow) * D_MODEL;
  const int rB1 = (srB1*16 + lrow) * D_MODEL;
  const int dA0 = srA0*2048 + lane*16;
  const int dA1 = srA1*2048 + lane*16;
  const int dB0 = 65536 + srB0*2048 + lane*16;
  const int dB1 = 65536 + srB1*2048 + lane*16;

  floatx4 acc[8][4] = {};
  bf16x8 aflo[4][2], afhi[4][2], bfr1[2][2], bfr0_e[2][2], bfr0_o[2][2];

  // prologue: queue order {Bu1(0),Au0(0),Bu0(0),Au1(0),Au0(1),Bu0(1)};
  // VMW6 drains the first three -> prologue reads + tile0.tp0's bfr1 read
  // certified; leaves [Au1(0),Au0(1),Bu0(1)] = steady-state entry queue.
  STG(gB, rB1, dB1, 0);            // Bu1(0) -> buf0
  STG(gA, rA0, dA0, 0);            // Au0(0) -> buf0
  STG(gB, rB0, dB0, 0);            // Bu0(0) -> buf0
  STG(gA, rA1, dA1, 0);            // Au1(0) -> buf0
  STG(gA, rA0, 32768 + dA0, 1);    // Au0(1) -> buf1
  STG(gB, rB0, 32768 + dB0, 1);    // Bu0(1) -> buf1
  VMW6;
  BAR;
  RD_A(0, 0, aflo);                // afr_lo(0)
  RD_B(0, 0, bfr0_e);              // bfr0(0)

#pragma unroll 1
  for (int p = 0; p < 15; ++p) {   // tiles 0..29
    KTILE_F(0, 2*p+1, 2*p+2, bfr0_e, bfr0_o);
    KTILE_F(1, 2*p+2, 2*p+3, bfr0_o, bfr0_e);
  }
  KTILE_T30(0, 31, bfr0_e, bfr0_o);   // tile 30
  KTILE_T31(1, bfr0_o);               // tile 31

  // ======================= fused scan epilogue (R4, verified) ==============
  const int mW0 = m0 + wM*128;
  const int nW0 = n0 + wN*64;
  const float alpha = alphas[nW0 >> 8];
  const float a2 = alpha*alpha, a4 = a2*a2, a8 = a4*a4, a16 = a8*a8, a32 = a16*a16;
  const float a64 = a32*a32, a128 = a64*a64;
  const float a256 = a128*a128, a512 = a256*a256, a1024 = a512*a512;
  float aq = 1.f;                      // alpha^(12-4lq)
#pragma unroll
  for (int i = 0; i < 3; ++i) if (i < 3 - lq) aq *= a4;
  float a4p = 1.f;                     // alpha^(4*lq)
#pragma unroll
  for (int i = 0; i < 3; ++i) if (i < lq) a4p *= a4;
  const int bb  = mW0 >> 12;               // batch
  const int j0w = (mW0 & (SEQ - 1)) >> 5;  // wave's first 32-chunk (uniform)
  const int jw  = j0w >> 2;                // wave-carry index, 0..63
  float* wcb = wc + (size_t)bb * NWAVEC * NOUT;

  // ---- A) chunk carries in-register + per-wave carry publication ----
  float bvv[4], tmv[4][8], rcl[4][4];
#pragma unroll
  for (int nf = 0; nf < 4; ++nf) {
    const int n = nW0 + nf*16 + lr;
    bvv[nf] = bias[n];
    const float bv = bvv[nf];
#pragma unroll
    for (int mf = 0; mf < 8; ++mf) {
      const floatx4 av = acc[mf][nf];
      tmv[nf][mf] = (((av[0]+bv)*alpha + (av[1]+bv))*alpha + (av[2]+bv))*alpha + (av[3]+bv);
    }
#pragma unroll
    for (int c = 0; c < 4; ++c) {
      float s = (tmv[nf][2*c]*a16 + tmv[nf][2*c+1]) * aq;
      s += __shfl_xor(s, 16, 64);
      s += __shfl_xor(s, 32, 64);
      rcl[nf][c] = s;                  // full chunk carry, ALL lanes
    }
    const float Wv = ((rcl[nf][0]*a32 + rcl[nf][1])*a32 + rcl[nf][2])*a32 + rcl[nf][3];
    if (lq == 0)
      __hip_atomic_store(&wcb[(size_t)jw*NOUT + n], Wv,
                         __ATOMIC_RELAXED, __HIP_MEMORY_SCOPE_AGENT);
  }

  // ---- B) device barrier across the 32 bx-blocks of this by-slice ----
  __syncthreads();
  if (t == 0) {
    __hip_atomic_fetch_add(&ctr[blockIdx.y], 1, __ATOMIC_ACQ_REL, __HIP_MEMORY_SCOPE_AGENT);
    while (__hip_atomic_load(&ctr[blockIdx.y], __ATOMIC_ACQUIRE, __HIP_MEMORY_SCOPE_AGENT) < 32)
      __builtin_amdgcn_s_sleep(2);
  }
  __syncthreads();

  // ---- C) prefix over wave carries (8-deep batched), then in-reg apply ----
  {
    const float* wcl = wcb + (nW0 + lq*16 + lr);   // lane's column
    float H = 0.f;
    int jp = 0;
    for (; jp + 8 <= jw; jp += 8) {
      float v[8];
#pragma unroll
      for (int i = 0; i < 8; ++i)
        v[i] = CARRY_LD(&wcl[(size_t)(jp + i)*NOUT]);
      float h = v[0];
#pragma unroll
      for (int i = 1; i < 8; ++i) h = h*a128 + v[i];
      H = H*a1024 + h;
    }
    for (; jp < jw; ++jp)
      H = H*a128 + CARRY_LD(&wcl[(size_t)jp*NOUT]);

    float s0[4];
#pragma unroll
    for (int nf = 0; nf < 4; ++nf) s0[nf] = __shfl(H, nf*16 + lr, 64);

#pragma unroll
    for (int nf = 0; nf < 4; ++nf) {
      const int n = nW0 + nf*16 + lr;
      const float bv = bvv[nf];
      float sp = s0[nf];               // carry-in to chunk j0w
#pragma unroll
      for (int c = 0; c < 4; ++c) {
        if (c > 0)
          sp = a32*sp + rcl[nf][c-1];  // own chunk carry, in-register
        float ulo[4], uhi[4];
#pragma unroll
        for (int i = 0; i < 4; ++i) {
          ulo[i] = acc[2*c][nf][i]   + bv;
          uhi[i] = acc[2*c+1][nf][i] + bv;
        }
        const float Tlo = tmv[nf][2*c];
        const float Thi = tmv[nf][2*c+1];
        const float t0  = __shfl(Tlo, lr,      64);
        const float t1  = __shfl(Tlo, 16 + lr, 64);
        const float t2  = __shfl(Tlo, 32 + lr, 64);
        const float t3  = __shfl(Tlo, 48 + lr, 64);
        const float th0 = __shfl(Thi, lr,      64);
        const float th1 = __shfl(Thi, 16 + lr, 64);
        const float th2 = __shfl(Thi, 32 + lr, 64);
        float h = 0.f;
        if (lq > 0) h = t0;
        if (lq > 1) h = h*a4 + t1;
        if (lq > 2) h = h*a4 + t2;
        float Slo = a4p*sp + h;
        const float smid = (((t0*a4 + t1)*a4 + t2)*a4 + t3) + a16*sp;
        float hh = 0.f;
        if (lq > 0) hh = th0;
        if (lq > 1) hh = hh*a4 + th1;
        if (lq > 2) hh = hh*a4 + th2;
        float Shi = a4p*smid + hh;
        const size_t rowb = (size_t)(mW0 + 2*c*16 + lq*4);
        float s = Slo;
#pragma unroll
        for (int i = 0; i < 4; ++i) { s = alpha*s + ulo[i]; C[(rowb + i)*NOUT + n] = s; }
        s = Shi;
#pragma unroll
        for (int i = 0; i < 4; ++i) { s = alpha*s + uhi[i]; C[(rowb + 16 + i)*NOUT + n] = s; }
      }
    }
  }
}

// ---------------------------------------------------------------------------
extern "C" void kernel_launch(void* const* d_in, const int* in_sizes, int n_in,
                              void* d_out, int out_size, void* d_ws, size_t ws_size,
                              hipStream_t stream) {
  const float* x      = (const float*)d_in[0];
  const float* W      = (const float*)d_in[1];
  const float* bias   = (const float*)d_in[2];
  const float* alphas = (const float*)d_in[3];
  float* out = (float*)d_out;

  // workspace: xb 33,554,432 | wb 8,388,608 | wc 1,048,576 | ctr 32B
  __bf16* xb = (__bf16*)d_ws;
  __bf16* wb = (__bf16*)((char*)d_ws + (size_t)M_TOTAL * D_MODEL * 2);
  float* wc  = (float*)((char*)d_ws + (size_t)M_TOTAL * D_MODEL * 2
                                     + (size_t)NOUT * D_MODEL * 2);
  int* ctr   = (int*)((char*)d_ws + (size_t)M_TOTAL * D_MODEL * 2
                                   + (size_t)NOUT * D_MODEL * 2
                                   + (size_t)BATCH * NWAVEC * NOUT * 4);

  // 1) cast fp32 -> bf16 (+ zero barrier counters)
  {
    const long long total = ((long long)M_TOTAL * D_MODEL + (long long)NOUT * D_MODEL) / 4;
    const int blocks = (int)((total + 255) / 256);  // 20480
    cast_kernel<<<blocks, 256, 0, stream>>>(x, W, xb, wb, ctr);
  }
  // 2) GEMM + fused full scan -> d_out holds final state. grid MUST stay 256
  //    blocks (1/CU via 128KiB LDS) for the device-barrier co-residency.
  {
    dim3 grid(M_TOTAL / 256, NOUT / 256);  // (32, 8)
    gemm_scan_kernel<<<grid, 512, 131072, stream>>>(xb, wb, bias, alphas, out, wc, ctr);
  }
}

// Round 7
// 198.653 us; speedup vs baseline: 1.5265x; 1.5265x over previous
//
#include <hip/hip_runtime.h>
#include <hip/hip_bf16.h>
#include <stdint.h>
#include <stddef.h>

#define D_MODEL 2048
#define NOUT    2048      // SLOTS * D_FIELD
#define BATCH   2
#define SEQ     4096
#define M_TOTAL (BATCH*SEQ)   // 8192
#define SLOTS   8
#define D_FIELD 256
#define CHUNK   32            // carry granularity (2 fragment rows)
#define NCHUNK  (SEQ/CHUNK)   // 128
#define NWAVEC  64            // per-batch wave-carry slots (128 rows each)

typedef __attribute__((ext_vector_type(4))) float  floatx4;
typedef __attribute__((ext_vector_type(8))) __bf16 bf16x8;
typedef __attribute__((ext_vector_type(4))) __bf16 bf16x4;

// ---------------------------------------------------------------------------
__device__ __forceinline__ void async_copy16(const void* gsrc, void* ldst) {
  __builtin_amdgcn_global_load_lds(
      (__attribute__((address_space(1))) const void*)(uintptr_t)gsrc,
      (__attribute__((address_space(3))) void*)(uintptr_t)ldst,
      16, 0, 0);
}

// ---------------------------------------------------------------------------
// Kernel 1: cast x and W fp32 -> bf16 into workspace; also zero barrier ctrs.
__global__ void cast_kernel(const float* __restrict__ x,
                            const float* __restrict__ W,
                            __bf16* __restrict__ xb,
                            __bf16* __restrict__ wb,
                            int* __restrict__ ctr) {
  if (blockIdx.x == 0 && threadIdx.x < 8)
    __hip_atomic_store(&ctr[threadIdx.x], 0, __ATOMIC_RELAXED, __HIP_MEMORY_SCOPE_AGENT);
  const long long nx = (long long)M_TOTAL * D_MODEL;  // 16777216
  const long long nw = (long long)NOUT * D_MODEL;     // 4194304
  long long base = ((long long)blockIdx.x * blockDim.x + threadIdx.x) * 4;
  if (base < nx) {
    float4 v = *(const float4*)(x + base);
    bf16x4 o;
    o[0] = (__bf16)v.x; o[1] = (__bf16)v.y; o[2] = (__bf16)v.z; o[3] = (__bf16)v.w;
    *(bf16x4*)(xb + base) = o;
  } else {
    long long j = base - nx;
    if (j < nw) {
      float4 v = *(const float4*)(W + j);
      bf16x4 o;
      o[0] = (__bf16)v.x; o[1] = (__bf16)v.y; o[2] = (__bf16)v.z; o[3] = (__bf16)v.w;
      *(bf16x4*)(wb + j) = o;
    }
  }
}

// ---------------------------------------------------------------------------
// Kernel 2: 256x256 8-phase GEMM + fused full scan.
// R7 = R4 (verified 77us) with the manual drains REMOVED (single axis):
//  - BAR is a raw s_barrier (NO sched_barrier(0): 8 motion-fences/tile gone)
//  - NO manual lgkmcnt(0): the ds_reads are compiler-visible loads, so the
//    compiler emits COUNTED lgkm waits per consuming MFMA (m97 asm evidence:
//    lgkmcnt(4/3/1/0)) -> first MFMAs start while later ds_reads are still in
//    flight = DS-pipe/MFMA-pipe overlap (what R6 tried by hand and spilled).
//    R4's all-drain + sched-fence per phase defeated exactly this.
// R6 lesson (reg budget): 8 waves/CU -> 256 unified regs/wave; acc=128 AGPR
// leaves 128 arch VGPRs. Fragment set must stay <= R4's (16 bf16x8 = 64).
// Overwrite safety without LGKM0: each wave's ds_reads of buf are consumed by
// MFMAs BEFORE that tile's tp3 BAR (counted waits precede each cluster), and
// the next tile's stages into that buf issue after that BAR and land >=200cy
// later -> no race. vmcnt certification identical to R4 (unchanged waits).
// ---------------------------------------------------------------------------
#define VMW4 asm volatile("s_waitcnt vmcnt(4)" ::: "memory")
#define VMW2 asm volatile("s_waitcnt vmcnt(2)" ::: "memory")
#define VMW0 asm volatile("s_waitcnt vmcnt(0)" ::: "memory")
#define BAR  __builtin_amdgcn_s_barrier()

#define DSRD(off) (*(const bf16x8*)(smem + (off)))

#define STG(GP, ROFF, DSTOFF, KTN) do{ \
  async_copy16((GP) + (ROFF) + (KTN)*64,      smem + (DSTOFF)); \
  async_copy16((GP) + (ROFF) + (KTN)*64 + 32, smem + (DSTOFF) + 1024); }while(0)

#define RD_AF(BUF, MOFF) do{ \
  _Pragma("unroll") for (int i_ = 0; i_ < 4; ++i_){ \
  _Pragma("unroll") for (int k_ = 0; k_ < 2; ++k_){ \
    afr[i_][k_] = DSRD((BUF)*32768 + ((wM8+(MOFF)+i_)*2+k_)*1024 + fragOff); }} }while(0)

#define RD_BF(BUF, NOFF, DST) do{ \
  _Pragma("unroll") for (int j_ = 0; j_ < 2; ++j_){ \
  _Pragma("unroll") for (int k_ = 0; k_ < 2; ++k_){ \
    DST[j_][k_] = DSRD(65536 + (BUF)*32768 + ((wN4+(NOFF)+j_)*2+k_)*1024 + fragOff); }} }while(0)

#define MFMA_Q(AM, AN, BFR) do{ \
  __builtin_amdgcn_s_setprio(1); \
  _Pragma("unroll") for (int i_ = 0; i_ < 4; ++i_){ \
  _Pragma("unroll") for (int j_ = 0; j_ < 2; ++j_){ \
  _Pragma("unroll") for (int k_ = 0; k_ < 2; ++k_){ \
    acc[(AM)+i_][(AN)+j_] = __builtin_amdgcn_mfma_f32_16x16x32_bf16( \
        afr[i_][k_], BFR[j_][k_], acc[(AM)+i_][(AN)+j_], 0, 0, 0); }}} \
  __builtin_amdgcn_s_setprio(0); }while(0)

#define KTILE(BUF, KTN, DO_STG) do{ \
  /* tp0 */ \
  RD_AF(BUF, 0); \
  RD_BF(BUF, 0, bfr0); \
  if (DO_STG) STG(gA, rA0, ((BUF)^1)*32768 + dA0, KTN); \
  if (DO_STG) { VMW4; } else { VMW2; } \
  BAR; \
  MFMA_Q(0, 0, bfr0); \
  /* tp1 */ \
  RD_BF(BUF, 2, bfr1); \
  if (DO_STG) STG(gB, rB0, ((BUF)^1)*32768 + dB0, KTN); \
  if (DO_STG) { VMW4; } else { VMW0; } \
  BAR; \
  MFMA_Q(0, 2, bfr1); \
  /* tp2 */ \
  RD_AF(BUF, 4); \
  if (DO_STG) STG(gB, rB1, ((BUF)^1)*32768 + dB1, KTN); \
  BAR; \
  MFMA_Q(4, 2, bfr1); \
  /* tp3 */ \
  if (DO_STG) { STG(gA, rA1, ((BUF)^1)*32768 + dA1, KTN); VMW4; } \
  BAR; \
  MFMA_Q(4, 0, bfr0); \
}while(0)

#define CARRY_LD(P) __hip_atomic_load((P), __ATOMIC_RELAXED, __HIP_MEMORY_SCOPE_AGENT)

__global__ __launch_bounds__(512, 2) void gemm_scan_kernel(
    const __bf16* __restrict__ A,    // [M_TOTAL, D_MODEL] bf16
    const __bf16* __restrict__ Bw,   // [NOUT, D_MODEL] bf16
    const float*  __restrict__ bias,
    const float*  __restrict__ alphas,
    float* __restrict__ C,           // [M_TOTAL, NOUT]  -> FINAL state
    float* __restrict__ wc,          // [BATCH, NWAVEC, NOUT] per-128-row carries
    int*   __restrict__ ctr) {       // [8] per-by barrier counters
  extern __shared__ __align__(16) char smem[];
  const int t    = threadIdx.x;
  const int lane = t & 63;
  const int w    = t >> 6;        // wave 0..7
  const int wM   = w >> 2;        // 0..1
  const int wN   = w & 3;         // 0..3
  const int m0   = blockIdx.x * 256;   // m fast -> A-panel's 8 n-blocks on one XCD
  const int n0   = blockIdx.y * 256;

  const int lq = lane >> 4, lr = lane & 15;
  const int fragOff = (lr*64 + lq*16) ^ (((lr >> 3) & 1) << 5);
  const int wM8 = wM*8, wN4 = wN*4;

  // staging: lane -> (row l>>2, pre-swizzled colOff) inside a 16x32 subtile
  const int lrow = lane >> 2;
  const int lcol = ((lane & 3) * 8) ^ ((lane >> 5) * 16);
  const int srA0 = (w & 3) + ((w >> 2) << 3), srA1 = srA0 + 4;
  const int srB0 = (w & 1) + ((w >> 1) << 2), srB1 = srB0 + 2;
  const __bf16* gA = A  + (size_t)m0 * D_MODEL + lcol;
  const __bf16* gB = Bw + (size_t)n0 * D_MODEL + lcol;
  const int rA0 = (srA0*16 + lrow) * D_MODEL;
  const int rA1 = (srA1*16 + lrow) * D_MODEL;
  const int rB0 = (srB0*16 + lrow) * D_MODEL;
  const int rB1 = (srB1*16 + lrow) * D_MODEL;
  const int dA0 = srA0*2048 + lane*16;
  const int dA1 = srA1*2048 + lane*16;
  const int dB0 = 65536 + srB0*2048 + lane*16;
  const int dB1 = 65536 + srB1*2048 + lane*16;

  floatx4 acc[8][4] = {};
  bf16x8 afr[4][2], bfr0[2][2], bfr1[2][2];

  // prologue: stage tile 0 into buf0 in order {Au0,Bu0,Bu1,Au1};
  // VMW4 drains Au0(0),Bu0(0) for tile0.tp0's reads.
  STG(gA, rA0, dA0, 0);
  STG(gB, rB0, dB0, 0);
  STG(gB, rB1, dB1, 0);
  STG(gA, rA1, dA1, 0);
  VMW4;
  BAR;

#pragma unroll 1
  for (int p = 0; p < 15; ++p) {       // tiles 0..29
    KTILE(0, 2*p+1, true);
    KTILE(1, 2*p+2, true);
  }
  KTILE(0, 31, true);                  // tile 30, stages tile 31
  KTILE(1, 0, false);                  // tile 31, drain (waits 2,0)

  // ======================= fused scan epilogue (R4, verified) ==============
  const int mW0 = m0 + wM*128;
  const int nW0 = n0 + wN*64;
  const float alpha = alphas[nW0 >> 8];
  const float a2 = alpha*alpha, a4 = a2*a2, a8 = a4*a4, a16 = a8*a8, a32 = a16*a16;
  const float a64 = a32*a32, a128 = a64*a64;
  const float a256 = a128*a128, a512 = a256*a256, a1024 = a512*a512;
  float aq = 1.f;                      // alpha^(12-4lq)
#pragma unroll
  for (int i = 0; i < 3; ++i) if (i < 3 - lq) aq *= a4;
  float a4p = 1.f;                     // alpha^(4*lq)
#pragma unroll
  for (int i = 0; i < 3; ++i) if (i < lq) a4p *= a4;
  const int bb  = mW0 >> 12;               // batch
  const int j0w = (mW0 & (SEQ - 1)) >> 5;  // wave's first 32-chunk (uniform)
  const int jw  = j0w >> 2;                // wave-carry index, 0..63
  float* wcb = wc + (size_t)bb * NWAVEC * NOUT;

  // ---- A) chunk carries in-register + per-wave carry publication ----
  float bvv[4], tmv[4][8], rcl[4][4];
#pragma unroll
  for (int nf = 0; nf < 4; ++nf) {
    const int n = nW0 + nf*16 + lr;
    bvv[nf] = bias[n];
    const float bv = bvv[nf];
#pragma unroll
    for (int mf = 0; mf < 8; ++mf) {
      const floatx4 av = acc[mf][nf];
      tmv[nf][mf] = (((av[0]+bv)*alpha + (av[1]+bv))*alpha + (av[2]+bv))*alpha + (av[3]+bv);
    }
#pragma unroll
    for (int c = 0; c < 4; ++c) {
      float s = (tmv[nf][2*c]*a16 + tmv[nf][2*c+1]) * aq;
      s += __shfl_xor(s, 16, 64);
      s += __shfl_xor(s, 32, 64);
      rcl[nf][c] = s;                  // full chunk carry, ALL lanes
    }
    const float Wv = ((rcl[nf][0]*a32 + rcl[nf][1])*a32 + rcl[nf][2])*a32 + rcl[nf][3];
    if (lq == 0)
      __hip_atomic_store(&wcb[(size_t)jw*NOUT + n], Wv,
                         __ATOMIC_RELAXED, __HIP_MEMORY_SCOPE_AGENT);
  }

  // ---- B) device barrier across the 32 bx-blocks of this by-slice ----
  __syncthreads();
  if (t == 0) {
    __hip_atomic_fetch_add(&ctr[blockIdx.y], 1, __ATOMIC_ACQ_REL, __HIP_MEMORY_SCOPE_AGENT);
    while (__hip_atomic_load(&ctr[blockIdx.y], __ATOMIC_ACQUIRE, __HIP_MEMORY_SCOPE_AGENT) < 32)
      __builtin_amdgcn_s_sleep(2);
  }
  __syncthreads();

  // ---- C) prefix over wave carries (8-deep batched), then in-reg apply ----
  {
    const float* wcl = wcb + (nW0 + lq*16 + lr);   // lane's column
    float H = 0.f;
    int jp = 0;
    for (; jp + 8 <= jw; jp += 8) {
      float v[8];
#pragma unroll
      for (int i = 0; i < 8; ++i)
        v[i] = CARRY_LD(&wcl[(size_t)(jp + i)*NOUT]);
      float h = v[0];
#pragma unroll
      for (int i = 1; i < 8; ++i) h = h*a128 + v[i];
      H = H*a1024 + h;
    }
    for (; jp < jw; ++jp)
      H = H*a128 + CARRY_LD(&wcl[(size_t)jp*NOUT]);

    float s0[4];
#pragma unroll
    for (int nf = 0; nf < 4; ++nf) s0[nf] = __shfl(H, nf*16 + lr, 64);

#pragma unroll
    for (int nf = 0; nf < 4; ++nf) {
      const int n = nW0 + nf*16 + lr;
      const float bv = bvv[nf];
      float sp = s0[nf];               // carry-in to chunk j0w
#pragma unroll
      for (int c = 0; c < 4; ++c) {
        if (c > 0)
          sp = a32*sp + rcl[nf][c-1];  // own chunk carry, in-register
        float ulo[4], uhi[4];
#pragma unroll
        for (int i = 0; i < 4; ++i) {
          ulo[i] = acc[2*c][nf][i]   + bv;
          uhi[i] = acc[2*c+1][nf][i] + bv;
        }
        const float Tlo = tmv[nf][2*c];
        const float Thi = tmv[nf][2*c+1];
        const float t0  = __shfl(Tlo, lr,      64);
        const float t1  = __shfl(Tlo, 16 + lr, 64);
        const float t2  = __shfl(Tlo, 32 + lr, 64);
        const float t3  = __shfl(Tlo, 48 + lr, 64);
        const float th0 = __shfl(Thi, lr,      64);
        const float th1 = __shfl(Thi, 16 + lr, 64);
        const float th2 = __shfl(Thi, 32 + lr, 64);
        float h = 0.f;
        if (lq > 0) h = t0;
        if (lq > 1) h = h*a4 + t1;
        if (lq > 2) h = h*a4 + t2;
        float Slo = a4p*sp + h;
        const float smid = (((t0*a4 + t1)*a4 + t2)*a4 + t3) + a16*sp;
        float hh = 0.f;
        if (lq > 0) hh = th0;
        if (lq > 1) hh = hh*a4 + th1;
        if (lq > 2) hh = hh*a4 + th2;
        float Shi = a4p*smid + hh;
        const size_t rowb = (size_t)(mW0 + 2*c*16 + lq*4);
        float s = Slo;
#pragma unroll
        for (int i = 0; i < 4; ++i) { s = alpha*s + ulo[i]; C[(rowb + i)*NOUT + n] = s; }
        s = Shi;
#pragma unroll
        for (int i = 0; i < 4; ++i) { s = alpha*s + uhi[i]; C[(rowb + 16 + i)*NOUT + n] = s; }
      }
    }
  }
}

// ---------------------------------------------------------------------------
extern "C" void kernel_launch(void* const* d_in, const int* in_sizes, int n_in,
                              void* d_out, int out_size, void* d_ws, size_t ws_size,
                              hipStream_t stream) {
  const float* x      = (const float*)d_in[0];
  const float* W      = (const float*)d_in[1];
  const float* bias   = (const float*)d_in[2];
  const float* alphas = (const float*)d_in[3];
  float* out = (float*)d_out;

  // workspace: xb 33,554,432 | wb 8,388,608 | wc 1,048,576 | ctr 32B
  __bf16* xb = (__bf16*)d_ws;
  __bf16* wb = (__bf16*)((char*)d_ws + (size_t)M_TOTAL * D_MODEL * 2);
  float* wc  = (float*)((char*)d_ws + (size_t)M_TOTAL * D_MODEL * 2
                                     + (size_t)NOUT * D_MODEL * 2);
  int* ctr   = (int*)((char*)d_ws + (size_t)M_TOTAL * D_MODEL * 2
                                   + (size_t)NOUT * D_MODEL * 2
                                   + (size_t)BATCH * NWAVEC * NOUT * 4);

  // 1) cast fp32 -> bf16 (+ zero barrier counters)
  {
    const long long total = ((long long)M_TOTAL * D_MODEL + (long long)NOUT * D_MODEL) / 4;
    const int blocks = (int)((total + 255) / 256);  // 20480
    cast_kernel<<<blocks, 256, 0, stream>>>(x, W, xb, wb, ctr);
  }
  // 2) GEMM + fused full scan -> d_out holds final state. grid MUST stay 256
  //    blocks (1/CU via 128KiB LDS) for the device-barrier co-residency.
  {
    dim3 grid(M_TOTAL / 256, NOUT / 256);  // (32, 8)
    gemm_scan_kernel<<<grid, 512, 131072, stream>>>(xb, wb, bias, alphas, out, wc, ctr);
  }
}